// Round 8
// baseline (197.329 us; speedup 1.0000x reference)
//
#include <hip/hip_runtime.h>
#include <hip/hip_bf16.h>

#define A_TOT 8400
#define NB 32
#define NG 16
#define NC 80

#define K1_GX 33                  // ceil(8400/256)
#define NWAVE (K1_GX * NB * 4)    // per-wave conf partials
#define K3_CH 8                   // anchor chunks per batch
#define K3_W  1050                // anchors per chunk (8*1050 = 8400)
#define K3_BLOCKS (K3_CH * NB)

#define L2E 1.44269504088896340736f
#define LN2 0.69314718055994530942f

// ---------- fast native transcendentals ----------
__device__ inline float fexp2(float x) { return __builtin_amdgcn_exp2f(x); }
__device__ inline float flog2(float x) { return __builtin_amdgcn_logf(x); }
__device__ inline float frcp(float x)  { return __builtin_amdgcn_rcpf(x); }
__device__ inline float fsqrtf_(float x) { return __builtin_amdgcn_sqrtf(x); }

__device__ inline float iou_cxcywh(float acx, float acy, float aw, float ah,
                                   float bcx, float bcy, float bw, float bh) {
    float tlx = fmaxf(acx - aw * 0.5f, bcx - bw * 0.5f);
    float tly = fmaxf(acy - ah * 0.5f, bcy - bh * 0.5f);
    float brx = fminf(acx + aw * 0.5f, bcx + bw * 0.5f);
    float bry = fminf(acy + ah * 0.5f, bcy + bh * 0.5f);
    float w = fmaxf(brx - tlx, 0.0f);
    float h = fmaxf(bry - tly, 0.0f);
    float inter = w * h;
    return inter / (aw * ah + bw * bh - inter + 1e-16f);
}

// d = logp - log1mp for class logit x and conf-sigmoid sc  (shared by k2/k3 -> consistent)
__device__ inline float dval_of(float x, float sc) {
    float u = fexp2(-x * L2E);
    float sx = frcp(1.0f + u);
    float pr = fsqrtf_(sx * sc);
    float lp  = fmaxf(LN2 * flog2(fmaxf(pr, 1e-12f)), -100.0f);
    float l1p = fmaxf(LN2 * flog2(fmaxf(1.0f - pr, 1e-12f)), -100.0f);
    return lp - l1p;
}

// cost for (g, a); m = umask word (bit16 = union, bits0..15 = inter per g)
__device__ inline float cost_fast(float iou, float d, float sp, unsigned m, int g) {
    if (!((m >> 16) & 1u)) return 1e15f;
    float c = -(d + sp) - 3.0f * LN2 * flog2(iou + 1e-8f);
    if (!((m >> g) & 1u)) c += 100000.0f;
    return c;
}

__device__ inline unsigned long long umax64(unsigned long long a, unsigned long long b) {
    return a > b ? a : b;
}
__device__ inline unsigned long long umin64(unsigned long long a, unsigned long long b) {
    return a < b ? a : b;
}

// resolve anchor index -> level base / hw / HW / W / stride
__device__ inline const float* lvl_base(int a, int b, const float* p8, const float* p16,
                                        const float* p32, int& hw, int& HW, int& W, float& s) {
    if (a < 6400) { hw = a;        HW = 6400; W = 80; s = 8.0f;  return p8  + (size_t)b * 85 * 6400; }
    if (a < 8000) { hw = a - 6400; HW = 1600; W = 40; s = 16.0f; return p16 + (size_t)b * 85 * 1600; }
    { hw = a - 8000; HW = 400; W = 20; s = 32.0f; return p32 + (size_t)b * 85 * 400; }
}

// ---------- kernel 1: decode + masks; compacted class-sum for union anchors ----------
// rec[i] = {umask(bits), sigmoid(conf), sum log1mp (union only), conf logit}
// cmp[b*A_TOT .. +cnt[b]) = union anchor indices (order arbitrary; selection is
// order-independent since keys embed the index).
__global__ __launch_bounds__(256, 4) void k1_decode(
    const float* __restrict__ p8, const float* __restrict__ p16, const float* __restrict__ p32,
    const float* __restrict__ gtb,
    float4* __restrict__ pbox, float4* __restrict__ rec,
    int* __restrict__ cmp, int* __restrict__ cnt, float* __restrict__ part) {
    __shared__ int lcnt, base_s;
    __shared__ int list[256];
    __shared__ float scl[256];
    int b = blockIdx.y;
    int tid = threadIdx.x;
    int a = blockIdx.x * 256 + tid;
    bool valid = a < A_TOT;
    if (tid == 0) lcnt = 0;
    __syncthreads();

    float bce0_conf = 0.0f;
    int myslot = -1;
    if (valid) {
        int hw, HW, W;
        float s;
        const float* base = lvl_base(a, b, p8, p16, p32, hw, HW, W, s);

        float tx = base[hw], ty = base[HW + hw];
        float tw = base[2 * HW + hw], th = base[3 * HW + hw];
        float cf = base[4 * HW + hw];
        int gx = hw % W, gy = hw / W;
        float pcx = (tx + (float)gx) * s;
        float pcy = (ty + (float)gy) * s;
        float pw = fexp2(tw * L2E) * s;
        float ph = fexp2(th * L2E) * s;

        float uc = fexp2(-cf * L2E);          // e^{-cf}
        float suc = 1.0f + uc;
        float sc = frcp(suc);
        bce0_conf = cf + LN2 * flog2(suc);    // log(1+e^cf) = bce0(conf)

        // union / inter masks
        float xc = ((float)gx + 0.5f) * s;
        float yc = ((float)gy + 0.5f) * s;
        unsigned m = 0;
        bool uni = false;
        float r = 2.5f * s;
#pragma unroll 4
        for (int g = 0; g < NG; g++) {
            float gcx = gtb[(b * NG + g) * 4 + 0];
            float gcy = gtb[(b * NG + g) * 4 + 1];
            float gw  = gtb[(b * NG + g) * 4 + 2];
            float gh  = gtb[(b * NG + g) * 4 + 3];
            bool ib = (xc > gcx - gw * 0.5f) && (gcx + gw * 0.5f > xc) &&
                      (yc > gcy - gh * 0.5f) && (gcy + gh * 0.5f > yc);
            bool im = (xc > gcx - r) && (gcx + r > xc) &&
                      (yc > gcy - r) && (gcy + r > yc);
            uni |= (ib || im);
            if (ib && im) m |= (1u << g);
        }
        if (uni) {
            m |= (1u << 16);
            myslot = atomicAdd(&lcnt, 1);
            list[myslot] = tid;
            scl[myslot] = sc;
        }
        size_t i = (size_t)b * A_TOT + a;
        pbox[i] = make_float4(pcx, pcy, pw, ph);
        rec[i] = make_float4(__uint_as_float(m), sc, 0.0f, cf);
    }
    __syncthreads();
    int n = lcnt;
    if (tid == 0) base_s = atomicAdd(&cnt[b], n);
    __syncthreads();
    if (myslot >= 0) cmp[(size_t)b * A_TOT + base_s + myslot] = a;

    // phase B: class-sum for the block's union anchors; 4 lanes per anchor
    for (int t = tid; t < n * 4; t += 256) {
        int slot = t >> 2, q = t & 3;
        int lt = list[slot];
        int aa = blockIdx.x * 256 + lt;
        float sc2 = scl[slot];
        int hw, HW, W;
        float s;
        const float* base = lvl_base(aa, b, p8, p16, p32, hw, HW, W, s);
        const float* cbase = base + (5 + q * 20) * HW + hw;
        float x[20];
#pragma unroll
        for (int j = 0; j < 20; j++) x[j] = cbase[j * HW];
        float suml1p = 0.0f;
#pragma unroll
        for (int j = 0; j < 20; j++) {
            float u = fexp2(-x[j] * L2E);
            float pr = fsqrtf_(frcp(1.0f + u) * sc2);
            suml1p += fmaxf(LN2 * flog2(fmaxf(1.0f - pr, 1e-12f)), -100.0f);
        }
        suml1p += __shfl_xor(suml1p, 1, 64);
        suml1p += __shfl_xor(suml1p, 2, 64);
        if (q == 0) {
            float* recf = (float*)rec;
            recf[((size_t)b * A_TOT + aa) * 4 + 2] = suml1p;
        }
    }

    // wave-reduce bce0(conf), one store per wave (no atomics)
    float v = bce0_conf;
    for (int off = 32; off; off >>= 1) v += __shfl_down(v, off, 64);
    if ((tid & 63) == 0) {
        int wave = (blockIdx.y * gridDim.x + blockIdx.x) * 4 + (tid >> 6);
        part[wave] = v;
    }
}

// ---------- kernel 2: per-(b,g) dual top-10 over the COMPACTED union list ----------
// Non-union anchors can never enter either top-10 (iou_m=0 / cost=1e15 vs
// >=25 union anchors per GT), so scanning cmp[] is exact.
// 256 threads, min 4 waves/EU -> VGPR cap 128: u64 lists stay in registers.
__global__ __launch_bounds__(256, 4) void k2_assign(
    const float* __restrict__ gtb, const int* __restrict__ gtc,
    const float4* __restrict__ pbox, const float4* __restrict__ rec,
    const int* __restrict__ cmp, const int* __restrict__ cnt,
    const float* __restrict__ p8, const float* __restrict__ p16, const float* __restrict__ p32,
    int* __restrict__ sel, int* __restrict__ nsel) {
    __shared__ unsigned long long wred[4];
    int blk = blockIdx.x;            // b*16+g
    int b = blk >> 4, g = blk & 15;
    int tid = threadIdx.x;

    float gcx = gtb[blk * 4 + 0], gcy = gtb[blk * 4 + 1];
    float gw = gtb[blk * 4 + 2],  gh = gtb[blk * 4 + 3];
    int cg = gtc[blk];               // block-uniform class id
    int n = cnt[b];

    unsigned long long topI[10];   // masked-iou keys, descending
    unsigned long long topC[10];   // cost keys, ascending
#pragma unroll
    for (int i = 0; i < 10; i++) { topI[i] = 0ull; topC[i] = 0xFFFFFFFFFFFFFFFFull; }

    for (int j = tid; j < n; j += 256) {
        int a = cmp[(size_t)b * A_TOT + j];
        size_t i = (size_t)b * A_TOT + a;
        float4 pb = pbox[i];
        float4 rc = rec[i];
        unsigned m = __float_as_uint(rc.x);
        float iou = iou_cxcywh(gcx, gcy, gw, gh, pb.x, pb.y, pb.z, pb.w);

        int hw, HW, W;
        float s;
        const float* base = lvl_base(a, b, p8, p16, p32, hw, HW, W, s);
        float x = base[(5 + cg) * HW + hw];
        float d = dval_of(x, rc.y);
        float cost = -(d + rc.z) - 3.0f * LN2 * flog2(iou + 1e-8f);
        if (!((m >> g) & 1u)) cost += 100000.0f;

        if (iou > 0.0f) {
            unsigned long long kI = ((unsigned long long)__float_as_uint(iou) << 32) | (unsigned)a;
            if (kI > topI[9]) {
                unsigned long long v = kI;
#pragma unroll
                for (int i2 = 0; i2 < 10; i2++) {
                    unsigned long long big = umax64(topI[i2], v);
                    v = umin64(topI[i2], v);
                    topI[i2] = big;
                }
            }
        }
        unsigned long long kC = ((unsigned long long)__float_as_uint(cost) << 32) | (unsigned)a;
        if (kC < topC[9]) {
            unsigned long long v = kC;
#pragma unroll
            for (int i2 = 0; i2 < 10; i2++) {
                unsigned long long sml = umin64(topC[i2], v);
                v = umax64(topC[i2], v);
                topC[i2] = sml;
            }
        }
    }

    // ---- tournament 1: sum of global top-10 masked iou (descending) ----
    float ksum = 0.0f;
    for (int rr = 0; rr < 10; rr++) {
        unsigned long long h = topI[0];
        for (int off = 32; off; off >>= 1) h = umax64(h, __shfl_xor(h, off, 64));
        if ((tid & 63) == 0) wred[tid >> 6] = h;
        __syncthreads();
        unsigned long long w = umax64(umax64(wred[0], wred[1]), umax64(wred[2], wred[3]));
        ksum += __uint_as_float((unsigned)(w >> 32));
        if (topI[0] == w) {
#pragma unroll
            for (int i = 0; i < 9; i++) topI[i] = topI[i + 1];
            topI[9] = 0ull;
        }
        __syncthreads();
    }
    int dynk = (int)ksum;            // truncation matches astype(int32)
    if (dynk < 1) dynk = 1;
    if (dynk > 10) dynk = 10;

    // ---- tournament 2: 10 smallest costs (ascending, lowest-index ties) ----
    for (int rr = 0; rr < 10; rr++) {
        unsigned long long h = topC[0];
        for (int off = 32; off; off >>= 1) h = umin64(h, __shfl_xor(h, off, 64));
        if ((tid & 63) == 0) wred[tid >> 6] = h;
        __syncthreads();
        unsigned long long w = umin64(umin64(wred[0], wred[1]), umin64(wred[2], wred[3]));
        if (tid == 0) sel[blk * 10 + rr] = (int)(w & 0xffffffffu);
        if (topC[0] == w) {
#pragma unroll
            for (int i = 0; i < 9; i++) topC[i] = topC[i + 1];
            topC[9] = 0xFFFFFFFFFFFFFFFFull;
        }
        __syncthreads();
    }
    if (tid == 0) nsel[blk] = dynk;
}

// ---------- kernel 3: conflict resolution + loss partials + fused final reduce ----------
__global__ __launch_bounds__(256) void k3_resolve(
    const float* __restrict__ gtb, const int* __restrict__ gtc,
    const float4* __restrict__ pbox, const float4* __restrict__ rec,
    const int* __restrict__ sel, const int* __restrict__ nsel,
    const float* __restrict__ p8, const float* __restrict__ p16, const float* __restrict__ p32,
    const float* __restrict__ part, float4* __restrict__ part3,
    int* __restrict__ done, float* __restrict__ out) {
    __shared__ unsigned tag[K3_W];
    __shared__ float gb[NG * 4];
    __shared__ int gc[NG];
    __shared__ float red[256];
    __shared__ int islast;
    int b = blockIdx.y, chunk = blockIdx.x, tid = threadIdx.x;
    int a0 = chunk * K3_W;

    for (int j = tid; j < K3_W; j += 256) tag[j] = 0;
    if (tid < NG * 4) gb[tid] = gtb[b * NG * 4 + tid];
    if (tid < NG) gc[tid] = gtc[b * NG + tid];
    __syncthreads();

    if (tid < NG * 10) {
        int g = tid / 10, k = tid % 10;
        if (k < nsel[b * NG + g]) {
            int a = sel[(b * NG + g) * 10 + k];
            if (a >= a0 && a < a0 + K3_W)
                atomicAdd(&tag[a - a0], 0x10000u + (unsigned)(g + 1));
        }
    }
    __syncthreads();

    float lbox = 0.0f, lconfc = 0.0f, lcls = 0.0f, nfg = 0.0f;
    for (int j = tid; j < K3_W; j += 256) {
        unsigned t = tag[j];
        unsigned cnt2 = t >> 16;
        if (!cnt2) continue;
        int a = a0 + j;
        size_t i = (size_t)b * A_TOT + a;
        float4 pb = pbox[i];
        float4 rc = rec[i];
        int hw, HW, W;
        float s;
        const float* base = lvl_base(a, b, p8, p16, p32, hw, HW, W, s);
        int gs;
        if (cnt2 == 1) {
            gs = (int)(t & 0xffffu) - 1;
        } else {
            unsigned m = __float_as_uint(rc.x);
            float bc = 3.402823466e38f;
            gs = 0;
            for (int g = 0; g < NG; g++) {
                float iou = iou_cxcywh(gb[g * 4], gb[g * 4 + 1], gb[g * 4 + 2], gb[g * 4 + 3],
                                       pb.x, pb.y, pb.z, pb.w);
                float x = base[(5 + gc[g]) * HW + hw];
                float d = dval_of(x, rc.y);
                float c = cost_fast(iou, d, rc.z, m, g);
                if (c < bc) { bc = c; gs = g; }
            }
        }
        float miou = iou_cxcywh(gb[gs * 4], gb[gs * 4 + 1], gb[gs * 4 + 2], gb[gs * 4 + 3],
                                pb.x, pb.y, pb.z, pb.w);
        int cid = gc[gs];
        float xcid = base[(5 + cid) * HW + hw];

        // on-demand s0 = sum_c bce0(x_c)
        float s0 = 0.0f;
        const float* cbase = base + 5 * HW + hw;
#pragma unroll
        for (int cc = 0; cc < NC; cc += 20) {
            float x[20];
#pragma unroll
            for (int jj = 0; jj < 20; jj++) x[jj] = cbase[(cc + jj) * HW];
#pragma unroll
            for (int jj = 0; jj < 20; jj++) {
                float u = fexp2(-x[jj] * L2E);
                s0 += x[jj] + LN2 * flog2(1.0f + u);
            }
        }

        lbox += 1.0f - miou * miou;
        lconfc -= rc.w;
        lcls += s0 - xcid * miou;
        nfg += 1.0f;
    }

    // block reduce the four partials -> one float4 store
    float vals[4] = {lbox, lconfc, lcls, nfg};
    float outv[4];
    for (int i = 0; i < 4; i++) {
        red[tid] = vals[i];
        __syncthreads();
        for (int s2 = 128; s2 > 0; s2 >>= 1) {
            if (tid < s2) red[tid] += red[tid + s2];
            __syncthreads();
        }
        outv[i] = red[0];
        __syncthreads();
    }
    if (tid == 0)
        part3[b * K3_CH + chunk] = make_float4(outv[0], outv[1], outv[2], outv[3]);

    // last block performs the final reduction (replaces k4)
    __threadfence();
    if (tid == 0) islast = (atomicAdd(done, 1) == K3_BLOCKS - 1);
    __syncthreads();
    if (!islast) return;
    __threadfence();

    float v = 0.0f;
    for (int i = tid; i < NWAVE; i += 256) v += part[i];
    float4 p = part3[tid];               // exactly 256 entries
    float fvals[5] = {v, p.x, p.y, p.z, p.w};
    float tot[5];
    for (int i = 0; i < 5; i++) {
        red[tid] = fvals[i];
        __syncthreads();
        for (int s2 = 128; s2 > 0; s2 >>= 1) {
            if (tid < s2) red[tid] += red[tid + s2];
            __syncthreads();
        }
        tot[i] = red[0];
        __syncthreads();
    }
    if (tid == 0) {
        float nfg2 = tot[4];
        if (nfg2 < 1.0f) nfg2 = 1.0f;
        out[0] = (5.0f * tot[1] + (tot[0] + tot[2]) + tot[3]) / nfg2;
    }
}

// ---------- launch ----------
extern "C" void kernel_launch(void* const* d_in, const int* in_sizes, int n_in,
                              void* d_out, int out_size, void* d_ws, size_t ws_size,
                              hipStream_t stream) {
    const float* p8  = (const float*)d_in[0];
    const float* p16 = (const float*)d_in[1];
    const float* p32 = (const float*)d_in[2];
    const float* gtb = (const float*)d_in[3];
    const int*   gtc = (const int*)d_in[4];

    char* w = (char*)d_ws;
    float4* pbox = (float4*)w;                 w += (size_t)NB * A_TOT * sizeof(float4);
    float4* rec  = (float4*)w;                 w += (size_t)NB * A_TOT * sizeof(float4);
    int* cmp     = (int*)w;                    w += (size_t)NB * A_TOT * sizeof(int);
    int* sel     = (int*)w;                    w += (size_t)NB * NG * 10 * sizeof(int);
    int* nsel    = (int*)w;                    w += (size_t)NB * NG * sizeof(int);
    float* part  = (float*)w;                  w += (size_t)NWAVE * sizeof(float);
    float4* part3 = (float4*)w;                w += (size_t)K3_BLOCKS * sizeof(float4);
    int* ctrs    = (int*)w;                    w += (size_t)(NB + 1) * sizeof(int);
    int* cnt = ctrs;          // [NB]
    int* done = ctrs + NB;    // [1]

    hipMemsetAsync(ctrs, 0, (NB + 1) * sizeof(int), stream);
    k1_decode<<<dim3(K1_GX, NB), 256, 0, stream>>>(
        p8, p16, p32, gtb, pbox, rec, cmp, cnt, part);
    k2_assign<<<NB * NG, 256, 0, stream>>>(gtb, gtc, pbox, rec, cmp, cnt,
                                           p8, p16, p32, sel, nsel);
    k3_resolve<<<dim3(K3_CH, NB), 256, 0, stream>>>(gtb, gtc, pbox, rec,
                                                    sel, nsel, p8, p16, p32,
                                                    part, part3, done, (float*)d_out);
}

// Round 9
// 174.749 us; speedup vs baseline: 1.1292x; 1.1292x over previous
//
#include <hip/hip_runtime.h>
#include <hip/hip_bf16.h>

#define A_TOT 8400
#define NB 32
#define NG 16
#define NC 80

#define K1_GX 33                  // ceil(8400/256)
#define NWAVE (K1_GX * NB * 4)    // per-wave conf partials
#define K3_CH 8                   // anchor chunks per batch
#define K3_W  1050                // anchors per chunk (8*1050 = 8400)
#define K3_BLOCKS (K3_CH * NB)

#define L2E 1.44269504088896340736f
#define LN2 0.69314718055994530942f

// ---------- fast native transcendentals ----------
__device__ inline float fexp2(float x) { return __builtin_amdgcn_exp2f(x); }
__device__ inline float flog2(float x) { return __builtin_amdgcn_logf(x); }
__device__ inline float frcp(float x)  { return __builtin_amdgcn_rcpf(x); }
__device__ inline float fsqrtf_(float x) { return __builtin_amdgcn_sqrtf(x); }

__device__ inline float iou_cxcywh(float acx, float acy, float aw, float ah,
                                   float bcx, float bcy, float bw, float bh) {
    float tlx = fmaxf(acx - aw * 0.5f, bcx - bw * 0.5f);
    float tly = fmaxf(acy - ah * 0.5f, bcy - bh * 0.5f);
    float brx = fminf(acx + aw * 0.5f, bcx + bw * 0.5f);
    float bry = fminf(acy + ah * 0.5f, bcy + bh * 0.5f);
    float w = fmaxf(brx - tlx, 0.0f);
    float h = fmaxf(bry - tly, 0.0f);
    float inter = w * h;
    return inter / (aw * ah + bw * bh - inter + 1e-16f);
}

// d = logp - log1mp for class logit x and conf-sigmoid sc  (shared by k2/k3 -> consistent)
__device__ inline float dval_of(float x, float sc) {
    float u = fexp2(-x * L2E);
    float sx = frcp(1.0f + u);
    float pr = fsqrtf_(sx * sc);
    float lp  = fmaxf(LN2 * flog2(fmaxf(pr, 1e-12f)), -100.0f);
    float l1p = fmaxf(LN2 * flog2(fmaxf(1.0f - pr, 1e-12f)), -100.0f);
    return lp - l1p;
}

// cost for (g, a); m = umask word (bit16 = union, bits0..15 = inter per g)
__device__ inline float cost_fast(float iou, float d, float sp, unsigned m, int g) {
    if (!((m >> 16) & 1u)) return 1e15f;
    float c = -(d + sp) - 3.0f * LN2 * flog2(iou + 1e-8f);
    if (!((m >> g) & 1u)) c += 100000.0f;
    return c;
}

__device__ inline unsigned long long umax64(unsigned long long a, unsigned long long b) {
    return a > b ? a : b;
}
__device__ inline unsigned long long umin64(unsigned long long a, unsigned long long b) {
    return a < b ? a : b;
}

// resolve anchor index -> level base / hw / HW / W / stride
__device__ inline const float* lvl_base(int a, int b, const float* p8, const float* p16,
                                        const float* p32, int& hw, int& HW, int& W, float& s) {
    if (a < 6400) { hw = a;        HW = 6400; W = 80; s = 8.0f;  return p8  + (size_t)b * 85 * 6400; }
    if (a < 8000) { hw = a - 6400; HW = 1600; W = 40; s = 16.0f; return p16 + (size_t)b * 85 * 1600; }
    { hw = a - 8000; HW = 400; W = 20; s = 32.0f; return p32 + (size_t)b * 85 * 400; }
}

// ---------- kernel 1: decode + masks; predicated class-sum; union compaction ----------
// rec[i] = {umask(bits), sigmoid(conf), sum log1mp (union only), conf logit}
// cmp[b*A_TOT .. +cnt[b]) = union anchor indices (order arbitrary; selection is
// order-independent since keys embed the index).
__global__ __launch_bounds__(256) void k1_decode(
    const float* __restrict__ p8, const float* __restrict__ p16, const float* __restrict__ p32,
    const float* __restrict__ gtb,
    float4* __restrict__ pbox, float4* __restrict__ rec,
    int* __restrict__ cmp, int* __restrict__ cnt, float* __restrict__ part) {
    __shared__ int lcnt, base_s;
    int b = blockIdx.y;
    int tid = threadIdx.x;
    int a = blockIdx.x * 256 + tid;
    if (tid == 0) lcnt = 0;
    __syncthreads();

    float bce0_conf = 0.0f;
    int myslot = -1;
    if (a < A_TOT) {
        int hw, HW, W;
        float s;
        const float* base = lvl_base(a, b, p8, p16, p32, hw, HW, W, s);

        float tx = base[hw], ty = base[HW + hw];
        float tw = base[2 * HW + hw], th = base[3 * HW + hw];
        float cf = base[4 * HW + hw];
        int gx = hw % W, gy = hw / W;
        float pcx = (tx + (float)gx) * s;
        float pcy = (ty + (float)gy) * s;
        float pw = fexp2(tw * L2E) * s;
        float ph = fexp2(th * L2E) * s;

        float uc = fexp2(-cf * L2E);          // e^{-cf}
        float suc = 1.0f + uc;
        float sc = frcp(suc);
        bce0_conf = cf + LN2 * flog2(suc);    // log(1+e^cf) = bce0(conf)

        // union / inter masks
        float xc = ((float)gx + 0.5f) * s;
        float yc = ((float)gy + 0.5f) * s;
        unsigned m = 0;
        bool uni = false;
        float r = 2.5f * s;
#pragma unroll 4
        for (int g = 0; g < NG; g++) {
            float gcx = gtb[(b * NG + g) * 4 + 0];
            float gcy = gtb[(b * NG + g) * 4 + 1];
            float gw  = gtb[(b * NG + g) * 4 + 2];
            float gh  = gtb[(b * NG + g) * 4 + 3];
            bool ib = (xc > gcx - gw * 0.5f) && (gcx + gw * 0.5f > xc) &&
                      (yc > gcy - gh * 0.5f) && (gcy + gh * 0.5f > yc);
            bool im = (xc > gcx - r) && (gcx + r > xc) &&
                      (yc > gcy - r) && (gcy + r > yc);
            uni |= (ib || im);
            if (ib && im) m |= (1u << g);
        }
        if (uni) m |= (1u << 16);

        // sum log1mp over classes — consumed only where union is set.
        // Predicated, not compacted: union anchors are spatially clustered so
        // active lanes stay coalesced; R8's compacted phase-B scattered them.
        float suml1p = 0.0f;
        if (uni) {
            myslot = atomicAdd(&lcnt, 1);
            const float* cbase = base + 5 * HW + hw;
#pragma unroll
            for (int cc = 0; cc < NC; cc += 20) {
                float x[20];
#pragma unroll
                for (int j = 0; j < 20; j++) x[j] = cbase[(cc + j) * HW];
#pragma unroll
                for (int j = 0; j < 20; j++) {
                    float u = fexp2(-x[j] * L2E);
                    float pr = fsqrtf_(frcp(1.0f + u) * sc);
                    suml1p += fmaxf(LN2 * flog2(fmaxf(1.0f - pr, 1e-12f)), -100.0f);
                }
            }
        }

        size_t i = (size_t)b * A_TOT + a;
        pbox[i] = make_float4(pcx, pcy, pw, ph);
        rec[i] = make_float4(__uint_as_float(m), sc, suml1p, cf);
    }
    __syncthreads();
    if (tid == 0) base_s = atomicAdd(&cnt[b], lcnt);
    __syncthreads();
    if (myslot >= 0) cmp[(size_t)b * A_TOT + base_s + myslot] = a;

    // wave-reduce bce0(conf), one store per wave (no atomics)
    float v = bce0_conf;
    for (int off = 32; off; off >>= 1) v += __shfl_down(v, off, 64);
    if ((tid & 63) == 0) {
        int wave = (blockIdx.y * gridDim.x + blockIdx.x) * 4 + (tid >> 6);
        part[wave] = v;
    }
}

// ---------- kernel 2: per-(b,g) dual top-10 over the COMPACTED union list ----------
// Non-union anchors can never enter either top-10 (iou_m=0 / cost=1e15 vs
// >=25 union anchors per GT), so scanning cmp[] is exact.
__global__ __launch_bounds__(256, 4) void k2_assign(
    const float* __restrict__ gtb, const int* __restrict__ gtc,
    const float4* __restrict__ pbox, const float4* __restrict__ rec,
    const int* __restrict__ cmp, const int* __restrict__ cnt,
    const float* __restrict__ p8, const float* __restrict__ p16, const float* __restrict__ p32,
    int* __restrict__ sel, int* __restrict__ nsel) {
    __shared__ unsigned long long wred[4];
    int blk = blockIdx.x;            // b*16+g
    int b = blk >> 4, g = blk & 15;
    int tid = threadIdx.x;

    float gcx = gtb[blk * 4 + 0], gcy = gtb[blk * 4 + 1];
    float gw = gtb[blk * 4 + 2],  gh = gtb[blk * 4 + 3];
    int cg = gtc[blk];               // block-uniform class id
    int n = cnt[b];

    unsigned long long topI[10];   // masked-iou keys, descending
    unsigned long long topC[10];   // cost keys, ascending
#pragma unroll
    for (int i = 0; i < 10; i++) { topI[i] = 0ull; topC[i] = 0xFFFFFFFFFFFFFFFFull; }

    for (int j = tid; j < n; j += 256) {
        int a = cmp[(size_t)b * A_TOT + j];
        size_t i = (size_t)b * A_TOT + a;
        float4 pb = pbox[i];
        float4 rc = rec[i];
        unsigned m = __float_as_uint(rc.x);
        float iou = iou_cxcywh(gcx, gcy, gw, gh, pb.x, pb.y, pb.z, pb.w);

        int hw, HW, W;
        float s;
        const float* base = lvl_base(a, b, p8, p16, p32, hw, HW, W, s);
        float x = base[(5 + cg) * HW + hw];
        float d = dval_of(x, rc.y);
        float cost = -(d + rc.z) - 3.0f * LN2 * flog2(iou + 1e-8f);
        if (!((m >> g) & 1u)) cost += 100000.0f;

        if (iou > 0.0f) {
            unsigned long long kI = ((unsigned long long)__float_as_uint(iou) << 32) | (unsigned)a;
            if (kI > topI[9]) {
                unsigned long long v = kI;
#pragma unroll
                for (int i2 = 0; i2 < 10; i2++) {
                    unsigned long long big = umax64(topI[i2], v);
                    v = umin64(topI[i2], v);
                    topI[i2] = big;
                }
            }
        }
        unsigned long long kC = ((unsigned long long)__float_as_uint(cost) << 32) | (unsigned)a;
        if (kC < topC[9]) {
            unsigned long long v = kC;
#pragma unroll
            for (int i2 = 0; i2 < 10; i2++) {
                unsigned long long sml = umin64(topC[i2], v);
                v = umax64(topC[i2], v);
                topC[i2] = sml;
            }
        }
    }

    // ---- tournament 1: sum of global top-10 masked iou (descending) ----
    float ksum = 0.0f;
    for (int rr = 0; rr < 10; rr++) {
        unsigned long long h = topI[0];
        for (int off = 32; off; off >>= 1) h = umax64(h, __shfl_xor(h, off, 64));
        if ((tid & 63) == 0) wred[tid >> 6] = h;
        __syncthreads();
        unsigned long long w = umax64(umax64(wred[0], wred[1]), umax64(wred[2], wred[3]));
        ksum += __uint_as_float((unsigned)(w >> 32));
        if (topI[0] == w) {
#pragma unroll
            for (int i = 0; i < 9; i++) topI[i] = topI[i + 1];
            topI[9] = 0ull;
        }
        __syncthreads();
    }
    int dynk = (int)ksum;            // truncation matches astype(int32)
    if (dynk < 1) dynk = 1;
    if (dynk > 10) dynk = 10;

    // ---- tournament 2: 10 smallest costs (ascending, lowest-index ties) ----
    for (int rr = 0; rr < 10; rr++) {
        unsigned long long h = topC[0];
        for (int off = 32; off; off >>= 1) h = umin64(h, __shfl_xor(h, off, 64));
        if ((tid & 63) == 0) wred[tid >> 6] = h;
        __syncthreads();
        unsigned long long w = umin64(umin64(wred[0], wred[1]), umin64(wred[2], wred[3]));
        if (tid == 0) sel[blk * 10 + rr] = (int)(w & 0xffffffffu);
        if (topC[0] == w) {
#pragma unroll
            for (int i = 0; i < 9; i++) topC[i] = topC[i + 1];
            topC[9] = 0xFFFFFFFFFFFFFFFFull;
        }
        __syncthreads();
    }
    if (tid == 0) nsel[blk] = dynk;
}

// ---------- kernel 3: conflict resolution + loss partials (NO fences) ----------
__global__ __launch_bounds__(256) void k3_resolve(
    const float* __restrict__ gtb, const int* __restrict__ gtc,
    const float4* __restrict__ pbox, const float4* __restrict__ rec,
    const int* __restrict__ sel, const int* __restrict__ nsel,
    const float* __restrict__ p8, const float* __restrict__ p16, const float* __restrict__ p32,
    float4* __restrict__ part3) {
    __shared__ unsigned tag[K3_W];
    __shared__ float gb[NG * 4];
    __shared__ int gc[NG];
    __shared__ float red[256];
    int b = blockIdx.y, chunk = blockIdx.x, tid = threadIdx.x;
    int a0 = chunk * K3_W;

    for (int j = tid; j < K3_W; j += 256) tag[j] = 0;
    if (tid < NG * 4) gb[tid] = gtb[b * NG * 4 + tid];
    if (tid < NG) gc[tid] = gtc[b * NG + tid];
    __syncthreads();

    if (tid < NG * 10) {
        int g = tid / 10, k = tid % 10;
        if (k < nsel[b * NG + g]) {
            int a = sel[(b * NG + g) * 10 + k];
            if (a >= a0 && a < a0 + K3_W)
                atomicAdd(&tag[a - a0], 0x10000u + (unsigned)(g + 1));
        }
    }
    __syncthreads();

    float lbox = 0.0f, lconfc = 0.0f, lcls = 0.0f, nfg = 0.0f;
    for (int j = tid; j < K3_W; j += 256) {
        unsigned t = tag[j];
        unsigned cnt2 = t >> 16;
        if (!cnt2) continue;
        int a = a0 + j;
        size_t i = (size_t)b * A_TOT + a;
        float4 pb = pbox[i];
        float4 rc = rec[i];
        int hw, HW, W;
        float s;
        const float* base = lvl_base(a, b, p8, p16, p32, hw, HW, W, s);
        int gs;
        if (cnt2 == 1) {
            gs = (int)(t & 0xffffu) - 1;
        } else {
            unsigned m = __float_as_uint(rc.x);
            float bc = 3.402823466e38f;
            gs = 0;
            for (int g = 0; g < NG; g++) {
                float iou = iou_cxcywh(gb[g * 4], gb[g * 4 + 1], gb[g * 4 + 2], gb[g * 4 + 3],
                                       pb.x, pb.y, pb.z, pb.w);
                float x = base[(5 + gc[g]) * HW + hw];
                float d = dval_of(x, rc.y);
                float c = cost_fast(iou, d, rc.z, m, g);
                if (c < bc) { bc = c; gs = g; }
            }
        }
        float miou = iou_cxcywh(gb[gs * 4], gb[gs * 4 + 1], gb[gs * 4 + 2], gb[gs * 4 + 3],
                                pb.x, pb.y, pb.z, pb.w);
        int cid = gc[gs];
        float xcid = base[(5 + cid) * HW + hw];

        // on-demand s0 = sum_c bce0(x_c)
        float s0 = 0.0f;
        const float* cbase = base + 5 * HW + hw;
#pragma unroll
        for (int cc = 0; cc < NC; cc += 20) {
            float x[20];
#pragma unroll
            for (int jj = 0; jj < 20; jj++) x[jj] = cbase[(cc + jj) * HW];
#pragma unroll
            for (int jj = 0; jj < 20; jj++) {
                float u = fexp2(-x[jj] * L2E);
                s0 += x[jj] + LN2 * flog2(1.0f + u);
            }
        }

        lbox += 1.0f - miou * miou;
        lconfc -= rc.w;
        lcls += s0 - xcid * miou;
        nfg += 1.0f;
    }

    // block reduce the four partials -> one float4 store (no atomics)
    float vals[4] = {lbox, lconfc, lcls, nfg};
    float outv[4];
    for (int i = 0; i < 4; i++) {
        red[tid] = vals[i];
        __syncthreads();
        for (int s2 = 128; s2 > 0; s2 >>= 1) {
            if (tid < s2) red[tid] += red[tid + s2];
            __syncthreads();
        }
        outv[i] = red[0];
        __syncthreads();
    }
    if (tid == 0)
        part3[b * K3_CH + chunk] = make_float4(outv[0], outv[1], outv[2], outv[3]);
}

// ---------- kernel 4: sum partials + final scalar ----------
__global__ __launch_bounds__(256) void k4_final(
    const float* __restrict__ part, const float4* __restrict__ part3, float* __restrict__ out) {
    __shared__ float red[256];
    int tid = threadIdx.x;
    float v = 0.0f;
    for (int i = tid; i < NWAVE; i += 256) v += part[i];
    float4 p = part3[tid];               // exactly K3_BLOCKS = 256 entries
    float vals[5] = {v, p.x, p.y, p.z, p.w};
    float tot[5];
    for (int i = 0; i < 5; i++) {
        red[tid] = vals[i];
        __syncthreads();
        for (int s2 = 128; s2 > 0; s2 >>= 1) {
            if (tid < s2) red[tid] += red[tid + s2];
            __syncthreads();
        }
        tot[i] = red[0];
        __syncthreads();
    }
    if (tid == 0) {
        float nfg = tot[4];
        if (nfg < 1.0f) nfg = 1.0f;
        out[0] = (5.0f * tot[1] + (tot[0] + tot[2]) + tot[3]) / nfg;
    }
}

// ---------- launch ----------
extern "C" void kernel_launch(void* const* d_in, const int* in_sizes, int n_in,
                              void* d_out, int out_size, void* d_ws, size_t ws_size,
                              hipStream_t stream) {
    const float* p8  = (const float*)d_in[0];
    const float* p16 = (const float*)d_in[1];
    const float* p32 = (const float*)d_in[2];
    const float* gtb = (const float*)d_in[3];
    const int*   gtc = (const int*)d_in[4];

    char* w = (char*)d_ws;
    float4* pbox = (float4*)w;                 w += (size_t)NB * A_TOT * sizeof(float4);
    float4* rec  = (float4*)w;                 w += (size_t)NB * A_TOT * sizeof(float4);
    int* cmp     = (int*)w;                    w += (size_t)NB * A_TOT * sizeof(int);
    int* sel     = (int*)w;                    w += (size_t)NB * NG * 10 * sizeof(int);
    int* nsel    = (int*)w;                    w += (size_t)NB * NG * sizeof(int);
    float* part  = (float*)w;                  w += (size_t)NWAVE * sizeof(float);
    float4* part3 = (float4*)w;                w += (size_t)K3_BLOCKS * sizeof(float4);
    int* cnt     = (int*)w;                    w += (size_t)NB * sizeof(int);

    hipMemsetAsync(cnt, 0, NB * sizeof(int), stream);
    k1_decode<<<dim3(K1_GX, NB), 256, 0, stream>>>(
        p8, p16, p32, gtb, pbox, rec, cmp, cnt, part);
    k2_assign<<<NB * NG, 256, 0, stream>>>(gtb, gtc, pbox, rec, cmp, cnt,
                                           p8, p16, p32, sel, nsel);
    k3_resolve<<<dim3(K3_CH, NB), 256, 0, stream>>>(gtb, gtc, pbox, rec,
                                                    sel, nsel, p8, p16, p32, part3);
    k4_final<<<1, 256, 0, stream>>>(part, part3, (float*)d_out);
}